// Round 7
// baseline (526.589 us; speedup 1.0000x reference)
//
#include <hip/hip_runtime.h>

// Shapes (fixed): B=16, T_his=4095, T=4096, hid=2048, H=16, dh=128
// d_out layout (f32): K_out [16][4096][2048] | V_out [16][4096][2048] | v_next [16][2048]
// K_out[b][h*256 + t/16][(t%16)*128 + d] = K[b][t][h*128+d], K = concat(K_his, k_new)
// v_next = (sum_t V[b,t,:]) @ W_proj + b_proj   (softmax over size-1 axis == ones; q dead)

typedef float f4 __attribute__((ext_vector_type(4)));

__global__ void init_kernel(const float* __restrict__ b_attn,
                            const float* __restrict__ b_proj,
                            float* __restrict__ qkv,      // [16][4096] (k | v)
                            float* __restrict__ colsum,   // [16][2048]
                            float* __restrict__ vnext) {  // [16][2048] in d_out
  int tid = blockIdx.x * blockDim.x + threadIdx.x;   // 65536 threads
  qkv[tid] = b_attn[2048 + (tid & 4095)];            // bias for k,v columns
  if (tid < 32768) {
    colsum[tid] = 0.0f;
    vnext[tid] = b_proj[tid & 2047];
  }
}

// Partial GEMM: out[b][j] += X[16][2048] @ W[2048][ldw] (cols col0..col0+ncols)
__global__ void small_gemm_atomic(const float* __restrict__ X,
                                  const float* __restrict__ W,
                                  int ldw, int col0,
                                  float* __restrict__ out, int ncols) {
  int j  = blockIdx.x * 512 + threadIdx.x * 2;
  int k0 = blockIdx.y * 64;
  const float* wp = W + (size_t)k0 * ldw + col0 + j;
  float2 acc[16];
#pragma unroll
  for (int b = 0; b < 16; ++b) acc[b] = make_float2(0.f, 0.f);
  for (int kk = 0; kk < 64; ++kk) {
    float2 w = *(const float2*)(wp + (size_t)kk * ldw);
    const float* xp = X + k0 + kk;
#pragma unroll
    for (int b = 0; b < 16; ++b) {
      float xv = xp[(size_t)b * 2048];
      acc[b].x = fmaf(xv, w.x, acc[b].x);
      acc[b].y = fmaf(xv, w.y, acc[b].y);
    }
  }
#pragma unroll
  for (int b = 0; b < 16; ++b) {
    atomicAdd(&out[b * ncols + j],     acc[b].x);
    atomicAdd(&out[b * ncols + j + 1], acc[b].y);
  }
}

// Transposing copy, permutation folded into per-lane addressing (verified R6):
// lane l uses rowp = (l<32 ? row t0 : row t1); load i at rowp[i*256 + 4*(l&31)]
// is the store vector for head 2i (and +128 for head 2i+1). Reads stream full
// 8KB rows; writes are 1KB contiguous per instruction. No cross-lane, no barriers.
// K variant: lean (no colsum) for max occupancy.
__global__ void __launch_bounds__(256, 4)
copy_k(const float* __restrict__ K_his,
       const float* __restrict__ qkv,   // [16][4096] (k|v)
       float* __restrict__ out) {
  const int b   = blockIdx.y;
  const int gx  = blockIdx.x;
  const int tid = threadIdx.x;
  const int l   = tid & 63;
  const int w   = tid >> 6;
  const int off = 4 * (l & 31);
  const bool hi = (l >= 32);

  const float* srcb = K_his + (size_t)b * 8386560ull;   // 4095*2048
  const float* qsrc = qkv + b * 4096;                   // appended k row
  float* outb = out + ((size_t)b << 23);

  for (int gsub = 0; gsub < 2; ++gsub) {
    const int g = gx * 2 + gsub;
#pragma unroll
    for (int it = 0; it < 2; ++it) {
      const int rp = it * 4 + w;
      const int t0 = g * 16 + rp * 2;                   // even, <= 4094
      const float* r0 = srcb + (size_t)t0 * 2048u;
      const float* r1 = (t0 + 1 == 4095) ? qsrc : (r0 + 2048);
      const float* rowp = hi ? r1 : r0;

      f4 sa[8], sb[8];
#pragma unroll
      for (int i = 0; i < 8; ++i) {
        sa[i] = *(const f4*)(rowp + i * 256 + off);
        sb[i] = *(const f4*)(rowp + i * 256 + 128 + off);
      }
#pragma unroll
      for (int i = 0; i < 8; ++i) {
        float* o0 = outb + (size_t)(2 * i * 256 + g) * 2048u + (unsigned)(rp * 256 + 4 * l);
        *(f4*)o0 = sa[i];
        *(f4*)(o0 + 256 * 2048) = sb[i];
      }
    }
  }
}

// V variant: same copy + fused column-sum.
__global__ void __launch_bounds__(256, 3)
copy_v(const float* __restrict__ V_his,
       const float* __restrict__ qkv,
       float* __restrict__ out,
       float* __restrict__ colsum) {
  const int b   = blockIdx.y;
  const int gx  = blockIdx.x;
  const int tid = threadIdx.x;
  const int l   = tid & 63;
  const int w   = tid >> 6;
  const int off = 4 * (l & 31);
  const bool hi = (l >= 32);

  const float* srcb = V_his + (size_t)b * 8386560ull;
  const float* qsrc = qkv + b * 4096 + 2048;            // appended v row
  float* outb = out + (1ull << 27) + ((size_t)b << 23);

  __shared__ float lds[8192];

  f4 accA[8], accB[8];
#pragma unroll
  for (int i = 0; i < 8; ++i) {
    accA[i] = (f4){0.f, 0.f, 0.f, 0.f};
    accB[i] = (f4){0.f, 0.f, 0.f, 0.f};
  }

  for (int gsub = 0; gsub < 2; ++gsub) {
    const int g = gx * 2 + gsub;
#pragma unroll
    for (int it = 0; it < 2; ++it) {
      const int rp = it * 4 + w;
      const int t0 = g * 16 + rp * 2;
      const float* r0 = srcb + (size_t)t0 * 2048u;
      const float* r1 = (t0 + 1 == 4095) ? qsrc : (r0 + 2048);
      const float* rowp = hi ? r1 : r0;

      f4 sa[8], sb[8];
#pragma unroll
      for (int i = 0; i < 8; ++i) {
        sa[i] = *(const f4*)(rowp + i * 256 + off);
        sb[i] = *(const f4*)(rowp + i * 256 + 128 + off);
      }
#pragma unroll
      for (int i = 0; i < 8; ++i) { accA[i] += sa[i]; accB[i] += sb[i]; }
#pragma unroll
      for (int i = 0; i < 8; ++i) {
        float* o0 = outb + (size_t)(2 * i * 256 + g) * 2048u + (unsigned)(rp * 256 + 4 * l);
        *(f4*)o0 = sa[i];
        *(f4*)(o0 + 256 * 2048) = sb[i];
      }
    }
  }

  // lanes l and l^32 hold the same channels (t0-rows vs t1-rows): combine.
#pragma unroll
  for (int i = 0; i < 8; ++i) {
    accA[i].x += __shfl_xor(accA[i].x, 32);
    accA[i].y += __shfl_xor(accA[i].y, 32);
    accA[i].z += __shfl_xor(accA[i].z, 32);
    accA[i].w += __shfl_xor(accA[i].w, 32);
    accB[i].x += __shfl_xor(accB[i].x, 32);
    accB[i].y += __shfl_xor(accB[i].y, 32);
    accB[i].z += __shfl_xor(accB[i].z, 32);
    accB[i].w += __shfl_xor(accB[i].w, 32);
  }
  if (l < 32) {
#pragma unroll
    for (int i = 0; i < 8; ++i) {
      *(f4*)(&lds[w * 2048 + i * 256 + off])       = accA[i];
      *(f4*)(&lds[w * 2048 + i * 256 + 128 + off]) = accB[i];
    }
  }
  __syncthreads();
  const int c = tid * 8;
  f4 s0 = *(const f4*)(&lds[c]) + *(const f4*)(&lds[2048 + c])
        + *(const f4*)(&lds[4096 + c]) + *(const f4*)(&lds[6144 + c]);
  f4 s1 = *(const f4*)(&lds[c + 4]) + *(const f4*)(&lds[2048 + c + 4])
        + *(const f4*)(&lds[4096 + c + 4]) + *(const f4*)(&lds[6144 + c + 4]);
  float* cp = colsum + b * 2048 + c;
  atomicAdd(cp + 0, s0.x); atomicAdd(cp + 1, s0.y);
  atomicAdd(cp + 2, s0.z); atomicAdd(cp + 3, s0.w);
  atomicAdd(cp + 4, s1.x); atomicAdd(cp + 5, s1.y);
  atomicAdd(cp + 6, s1.z); atomicAdd(cp + 7, s1.w);
}

extern "C" void kernel_launch(void* const* d_in, const int* in_sizes, int n_in,
                              void* d_out, int out_size, void* d_ws, size_t ws_size,
                              hipStream_t stream) {
  const float* x      = (const float*)d_in[0];
  const float* K_his  = (const float*)d_in[1];
  const float* V_his  = (const float*)d_in[2];
  const float* W_attn = (const float*)d_in[3];
  const float* b_attn = (const float*)d_in[4];
  const float* W_proj = (const float*)d_in[5];
  const float* b_proj = (const float*)d_in[6];

  float* out    = (float*)d_out;
  float* qkv    = (float*)d_ws;            // 16*4096 f32 = 256 KB
  float* colsum = qkv + 16 * 4096;         // 16*2048 f32 = 128 KB
  float* vnext  = out + 268435456ull;      // third output region

  init_kernel<<<256, 256, 0, stream>>>(b_attn, b_proj, qkv, colsum, vnext);
  small_gemm_atomic<<<dim3(8, 32), 256, 0, stream>>>(x, W_attn, 6144, 2048, qkv, 4096);
  copy_k<<<dim3(128, 16), 256, 0, stream>>>(K_his, qkv, out);
  copy_v<<<dim3(128, 16), 256, 0, stream>>>(V_his, qkv, out, colsum);
  small_gemm_atomic<<<dim3(4, 32), 256, 0, stream>>>(colsum, W_proj, 2048, 0, vnext, 2048);
}

// Round 8
// 455.055 us; speedup vs baseline: 1.1572x; 1.1572x over previous
//
#include <hip/hip_runtime.h>

// Shapes (fixed): B=16, T_his=4095, T=4096, hid=2048, H=16, dh=128
// d_out layout (f32): K_out [16][4096][2048] | V_out [16][4096][2048] | v_next [16][2048]
// K_out[b][h*256 + g][(t%16)*128 + d] = K[b][t][h*128+d], g=t/16, K = concat(K_his, k_new)
// v_next = (sum_t V[b,t,:]) @ W_proj + b_proj   (softmax over size-1 axis == ones; q dead)

typedef float f4 __attribute__((ext_vector_type(4)));

__global__ void init_kernel(const float* __restrict__ b_attn,
                            const float* __restrict__ b_proj,
                            float* __restrict__ qkv,      // [16][4096] (k | v)
                            float* __restrict__ colsum,   // [16][2048]
                            float* __restrict__ vnext) {  // [16][2048] in d_out
  int tid = blockIdx.x * blockDim.x + threadIdx.x;   // 65536 threads
  qkv[tid] = b_attn[2048 + (tid & 4095)];            // bias for k,v columns
  if (tid < 32768) {
    colsum[tid] = 0.0f;
    vnext[tid] = b_proj[tid & 2047];
  }
}

// Partial GEMM: out[b][j] += X[16][2048] @ W[2048][ldw] (cols col0..col0+ncols)
__global__ void small_gemm_atomic(const float* __restrict__ X,
                                  const float* __restrict__ W,
                                  int ldw, int col0,
                                  float* __restrict__ out, int ncols) {
  int j  = blockIdx.x * 512 + threadIdx.x * 2;
  int k0 = blockIdx.y * 64;
  const float* wp = W + (size_t)k0 * ldw + col0 + j;
  float2 acc[16];
#pragma unroll
  for (int b = 0; b < 16; ++b) acc[b] = make_float2(0.f, 0.f);
  for (int kk = 0; kk < 64; ++kk) {
    float2 w = *(const float2*)(wp + (size_t)kk * ldw);
    const float* xp = X + k0 + kk;
#pragma unroll
    for (int b = 0; b < 16; ++b) {
      float xv = xp[(size_t)b * 2048];
      acc[b].x = fmaf(xv, w.x, acc[b].x);
      acc[b].y = fmaf(xv, w.y, acc[b].y);
    }
  }
#pragma unroll
  for (int b = 0; b < 16; ++b) {
    atomicAdd(&out[b * ncols + j],     acc[b].x);
    atomicAdd(&out[b * ncols + j + 1], acc[b].y);
  }
}

// Linear-both-sides transposing copy.
// Wave w of block x owns head-pair i = (x&1)*4 + w and t-groups g = (x>>1)*4 .. +3.
// Per row-pair (t0=g*16+2rp, t1=t0+1):
//   A = rowt0[i*256 + 4l]  (1KB contiguous; heads 2i (l<32) | 2i+1 (l>=32))
//   B = rowt1[i*256 + 4l]
//   H0 = l<32 ? A : shfl_xor(B,32)   -> out row (2i*256+g) at [rp*256+4l]  (1KB contig)
//   H1 = l<32 ? shfl_xor(A,32) : B   -> out row ((2i+1)*256+g)             (1KB contig)
// Wave writes two linear 8KB output rows per group. No LDS, no barriers.
// Colsum: acc channel is loop-invariant per lane = i*256+4l+c -> direct atomics.
// grid = (128, 16, 2 {K,V}).
__global__ void __launch_bounds__(256, 4)
copy_transpose(const float* __restrict__ K_his,
               const float* __restrict__ V_his,
               const float* __restrict__ qkv,   // [16][4096] (k|v)
               float* __restrict__ out,
               float* __restrict__ colsum) {
  const int b     = blockIdx.y;
  const int which = blockIdx.z;                 // 0=K, 1=V
  const int x     = blockIdx.x;
  const int tid   = threadIdx.x;
  const int l     = tid & 63;
  const int w     = tid >> 6;
  const int i     = (x & 1) * 4 + w;            // head-pair index 0..7
  const int gblk  = x >> 1;                     // 4 t-groups per block
  const bool hi   = (l >= 32);

  const float* src  = which ? V_his : K_his;
  const float* srcb = src + (size_t)b * 8386560ull + (unsigned)(i * 256 + 4 * l);
  const float* qsrc = qkv + b * 4096 + which * 2048 + i * 256 + 4 * l;
  float* outb = out + ((size_t)which << 27) + ((size_t)b << 23);

  f4 acc = {0.f, 0.f, 0.f, 0.f};

  for (int gs = 0; gs < 4; ++gs) {
    const int g = gblk * 4 + gs;
    float* row0 = outb + (size_t)(2 * i * 256 + g) * 2048u + (unsigned)(4 * l);
    float* row1 = row0 + 256 * 2048;
#pragma unroll
    for (int rp = 0; rp < 8; ++rp) {
      const int t0 = g * 16 + rp * 2;           // even, <= 4094
      const float* r0 = srcb + (size_t)t0 * 2048u;
      const float* r1 = (t0 + 1 == 4095) ? qsrc : (r0 + 2048);
      f4 A = __builtin_nontemporal_load((const f4*)r0);
      f4 B = __builtin_nontemporal_load((const f4*)r1);
      if (which) acc += A + B;
      f4 Ax, Bx;
#pragma unroll
      for (int c = 0; c < 4; ++c) {
        Ax[c] = __shfl_xor(A[c], 32);
        Bx[c] = __shfl_xor(B[c], 32);
      }
      f4 H0, H1;
#pragma unroll
      for (int c = 0; c < 4; ++c) {
        H0[c] = hi ? Bx[c] : A[c];
        H1[c] = hi ? B[c] : Ax[c];
      }
      __builtin_nontemporal_store(H0, (f4*)(row0 + rp * 256));
      __builtin_nontemporal_store(H1, (f4*)(row1 + rp * 256));
    }
  }

  if (which) {
    float* cp = colsum + b * 2048 + i * 256 + 4 * l;
    atomicAdd(cp + 0, acc.x);
    atomicAdd(cp + 1, acc.y);
    atomicAdd(cp + 2, acc.z);
    atomicAdd(cp + 3, acc.w);
  }
}

extern "C" void kernel_launch(void* const* d_in, const int* in_sizes, int n_in,
                              void* d_out, int out_size, void* d_ws, size_t ws_size,
                              hipStream_t stream) {
  const float* x      = (const float*)d_in[0];
  const float* K_his  = (const float*)d_in[1];
  const float* V_his  = (const float*)d_in[2];
  const float* W_attn = (const float*)d_in[3];
  const float* b_attn = (const float*)d_in[4];
  const float* W_proj = (const float*)d_in[5];
  const float* b_proj = (const float*)d_in[6];

  float* out    = (float*)d_out;
  float* qkv    = (float*)d_ws;            // 16*4096 f32 = 256 KB
  float* colsum = qkv + 16 * 4096;         // 16*2048 f32 = 128 KB
  float* vnext  = out + 268435456ull;      // third output region

  init_kernel<<<256, 256, 0, stream>>>(b_attn, b_proj, qkv, colsum, vnext);
  small_gemm_atomic<<<dim3(8, 32), 256, 0, stream>>>(x, W_attn, 6144, 2048, qkv, 4096);
  copy_transpose<<<dim3(128, 16, 2), 256, 0, stream>>>(K_his, V_his, qkv, out, colsum);
  small_gemm_atomic<<<dim3(4, 32), 256, 0, stream>>>(colsum, W_proj, 2048, 0, vnext, 2048);
}